// Round 1
// baseline (386.297 us; speedup 1.0000x reference)
//
#include <hip/hip_runtime.h>
#include <stdint.h>

// ---------------- common ----------------
#define BM 128
#define BN 128
#define BK 32
#define LDT 40  // BK + 8 pad (shorts): row stride 80B -> conflict-free-ish b128 reads

typedef __attribute__((ext_vector_type(8))) short bf16x8;
typedef __attribute__((ext_vector_type(4))) float f32x4;

__device__ __forceinline__ short f2bf(float f) {
  union { float f; uint32_t u; } v; v.f = f;
  return (short)((v.u + 0x7FFFu + ((v.u >> 16) & 1u)) >> 16);  // RNE
}
__device__ __forceinline__ float bf2f(uint16_t s) {
  union { uint32_t u; float f; } v; v.u = ((uint32_t)s) << 16;
  return v.f;
}

enum { A_F32 = 0, A_DUALK = 1, A_BF16 = 2, A_GATHER = 3 };
enum { E_PLAIN = 0, E_EDGE = 1, E_NODE = 2, E_PRED = 3 };

struct GemmArgs {
  const float* Af;      // fp32 A (lda = 512)
  const float* Af2;     // second A source for A_DUALK (k >= 512)
  const uint16_t* Ab;   // bf16 A for A_BF16
  const int* gidx;      // row gather for A_GATHER
  const float* B0;      // B rows [K,512] row-major; used for out cols < 512
  const float* B1;      // used for out cols >= 512 (N=1024 case)
  int K;
  float* Cf; int ldc;   // E_PLAIN out
  const float* bias;    // per-col bias
  const float* wattn;   // attention weight [512]
  const int* src; const int* dst; const int* toe;
  const float* A13;     // [4096,1024] (A1 | A3)
  const float* U13;     // [4096,1024] (U1 | U3)
  uint16_t* EF;         // e_f bf16 [61440,512]
  float* AATT;          // attn logit partial sums [61440]
  uint16_t* NNF;        // new_n_f bf16 [4096,512]
  float* OUT;           // pred fp32 [3840,512]
};

template <int AMODE, int EPI>
__global__ __launch_bounds__(256) void gemm_k(GemmArgs g) {
  __shared__ __align__(16) short As[BM * LDT];
  __shared__ __align__(16) short Bs[BN * LDT];
  const int tid = threadIdx.x;
  const int m0 = blockIdx.x * BM;
  const int n0g = blockIdx.y * BN;

  const float* Bp = g.B0;
  int n0 = n0g;
  if (n0g >= 512) { Bp = g.B1; n0 = n0g - 512; }

  // staging assignments (row constant across K loop)
  const int ar = tid >> 3;   // 0..31 (A row group)
  const int ak4 = tid & 7;   // 0..7  (A k float4 slot)
  const int bk = tid >> 5;   // 0..7  (B k row group)
  const int bn4 = tid & 31;  // 0..31 (B n float4 slot)

  const float* aptr[4]; const float* aptr2[4]; const uint16_t* abptr[4];
#pragma unroll
  for (int s = 0; s < 4; ++s) {
    int row = m0 + ar + 32 * s;
    if constexpr (AMODE == A_GATHER) row = g.gidx[row];
    if constexpr (AMODE == A_BF16) {
      abptr[s] = g.Ab + (size_t)row * 512;
    } else {
      aptr[s] = g.Af + (size_t)row * 512;
      if constexpr (AMODE == A_DUALK) aptr2[s] = g.Af2 + (size_t)row * 512;
    }
  }

  const int wid = tid >> 6, lane = tid & 63;
  const int wm = wid >> 1, wn = wid & 1;   // 2x2 waves, each 64x64
  const int lr = lane & 15, lg = lane >> 4;

  f32x4 acc[4][4] = {};

  for (int k0 = 0; k0 < g.K; k0 += BK) {
    __syncthreads();
    // ---- stage A: BM x BK, fp32->bf16 on the fly ----
#pragma unroll
    for (int s = 0; s < 4; ++s) {
      ushort4 w;
      if constexpr (AMODE == A_BF16) {
        w = *(const ushort4*)(abptr[s] + k0 + ak4 * 4);
      } else {
        const float* base; int kk;
        if constexpr (AMODE == A_DUALK) {
          base = (k0 < 512) ? aptr[s] : aptr2[s];
          kk = k0 & 511;
        } else { base = aptr[s]; kk = k0; }
        const float4 v = *(const float4*)(base + kk + ak4 * 4);
        w.x = (unsigned short)f2bf(v.x); w.y = (unsigned short)f2bf(v.y);
        w.z = (unsigned short)f2bf(v.z); w.w = (unsigned short)f2bf(v.w);
      }
      *(ushort4*)&As[(ar + 32 * s) * LDT + ak4 * 4] = w;
    }
    // ---- stage B: BK x BN, transposed into Bs[n][k] ----
#pragma unroll
    for (int s = 0; s < 4; ++s) {
      const int kk = bk + 8 * s;
      const float4 v = *(const float4*)(Bp + (size_t)(k0 + kk) * 512 + n0 + bn4 * 4);
      Bs[(bn4 * 4 + 0) * LDT + kk] = f2bf(v.x);
      Bs[(bn4 * 4 + 1) * LDT + kk] = f2bf(v.y);
      Bs[(bn4 * 4 + 2) * LDT + kk] = f2bf(v.z);
      Bs[(bn4 * 4 + 3) * LDT + kk] = f2bf(v.w);
    }
    __syncthreads();
    // ---- MFMA ----
    bf16x8 av[4], bv[4];
#pragma unroll
    for (int m = 0; m < 4; ++m)
      av[m] = *(const bf16x8*)&As[(wm * 64 + m * 16 + lr) * LDT + lg * 8];
#pragma unroll
    for (int n = 0; n < 4; ++n)
      bv[n] = *(const bf16x8*)&Bs[(wn * 64 + n * 16 + lr) * LDT + lg * 8];
#pragma unroll
    for (int m = 0; m < 4; ++m)
#pragma unroll
      for (int n = 0; n < 4; ++n)
        acc[m][n] = __builtin_amdgcn_mfma_f32_16x16x32_bf16(av[m], bv[n], acc[m][n], 0, 0, 0);
  }

  // ---- epilogue ----  C/D layout: col = lane&15, row = (lane>>4)*4 + reg
  const int rbase = m0 + wm * 64;
  const int cbase = n0g + wn * 64;

  if constexpr (EPI == E_PLAIN) {
#pragma unroll
    for (int m = 0; m < 4; ++m)
#pragma unroll
      for (int r = 0; r < 4; ++r) {
        const int row = rbase + m * 16 + lg * 4 + r;
#pragma unroll
        for (int n = 0; n < 4; ++n)
          g.Cf[(size_t)row * g.ldc + cbase + n * 16 + lr] = acc[m][n][r];
      }
  } else if constexpr (EPI == E_NODE) {
#pragma unroll
    for (int m = 0; m < 4; ++m)
#pragma unroll
      for (int r = 0; r < 4; ++r) {
        const int row = rbase + m * 16 + lg * 4 + r;
#pragma unroll
        for (int n = 0; n < 4; ++n) {
          const int col = cbase + n * 16 + lr;
          const float v = fmaxf(acc[m][n][r] + g.bias[col], 0.f);
          g.NNF[(size_t)row * 512 + col] = (uint16_t)f2bf(v);
        }
      }
  } else if constexpr (EPI == E_EDGE) {
    float bv[4], wv[4]; int cols[4];
#pragma unroll
    for (int n = 0; n < 4; ++n) {
      cols[n] = cbase + n * 16 + lr;
      bv[n] = g.bias[cols[n]];
      wv[n] = g.wattn[cols[n]];
    }
#pragma unroll
    for (int m = 0; m < 4; ++m)
#pragma unroll
      for (int r = 0; r < 4; ++r) {
        const int e = rbase + m * 16 + lg * 4 + r;
        const int se = g.src[e], de = g.dst[e];
        const float* a1 = g.A13 + (size_t)se * 1024;
        const float* a3 = g.A13 + (size_t)de * 1024 + 512;
        float rp = 0.f;
#pragma unroll
        for (int n = 0; n < 4; ++n) {
          float v = acc[m][n][r] + a1[cols[n]] + a3[cols[n]] + bv[n];
          v = fmaxf(v, 0.f);
          g.EF[(size_t)e * 512 + cols[n]] = (uint16_t)f2bf(v);
          rp += v * wv[n];
        }
        // sum over the 16 lanes holding this row's 16 (x4 frags=64) cols
        for (int d = 1; d < 16; d <<= 1) rp += __shfl_xor(rp, d);
        if (lr == 0) atomicAdd(&g.AATT[e], rp);
      }
  } else {  // E_PRED
    float bv[4]; int cols[4];
#pragma unroll
    for (int n = 0; n < 4; ++n) { cols[n] = cbase + n * 16 + lr; bv[n] = g.bias[cols[n]]; }
#pragma unroll
    for (int m = 0; m < 4; ++m)
#pragma unroll
      for (int r = 0; r < 4; ++r) {
        const int row = rbase + m * 16 + lg * 4 + r;
        const int te = g.toe[row];
        const int ts = g.src[te], td = g.dst[te];
        const float* u1 = g.U13 + (size_t)ts * 1024;
        const float* u3 = g.U13 + (size_t)td * 1024 + 512;
#pragma unroll
        for (int n = 0; n < 4; ++n) {
          const float v = acc[m][n][r] + u1[cols[n]] + u3[cols[n]] + bv[n];
          g.OUT[(size_t)row * 512 + cols[n]] = fmaxf(v, 0.f);
        }
      }
  }
}

// ---------- per-node softmax over 15 incoming edges + weighted aggregate ----------
__global__ __launch_bounds__(256) void node_reduce_k(const float* AATT, const float* battn,
                                                     const float* visual, const uint16_t* EF,
                                                     float* ZF) {
  const int v = blockIdx.x;
  const int gph = v >> 4, j = v & 15;
  __shared__ float sa[16];
  __shared__ float alf[16];
  __shared__ int eids[16];
  __shared__ int srcs[16];
  const int t = threadIdx.x;
  if (t < 15) {
    const int i = (t < j) ? t : t + 1;                 // the 15 src nodes (i != j)
    const int off = (j < i) ? j : (j - 1);
    const int eid = gph * 240 + i * 15 + off;          // DGL src-major edge id
    eids[t] = eid;
    srcs[t] = gph * 16 + i;
    sa[t] = fmaxf(AATT[eid] + battn[0], 0.f);          // a = relu(e_f.W_attn + b)
  }
  __syncthreads();
  float mx = -1e30f;
#pragma unroll
  for (int i = 0; i < 15; ++i) mx = fmaxf(mx, sa[i]);
  float den = 0.f;
#pragma unroll
  for (int i = 0; i < 15; ++i) den += expf(sa[i] - mx);
  if (t < 15) alf[t] = expf(sa[t] - mx) / den;
  __syncthreads();
  const int c = t * 2;  // 256 threads x 2 cols = 512
  float z0 = 0.f, z1 = 0.f;
#pragma unroll
  for (int i = 0; i < 15; ++i) {
    const float a = alf[i];
    const float2 vf = *(const float2*)(visual + (size_t)srcs[i] * 512 + c);
    const uint32_t ef = *(const uint32_t*)(EF + (size_t)eids[i] * 512 + c);
    z0 += a * (vf.x + bf2f((uint16_t)(ef & 0xFFFFu)));
    z1 += a * (vf.y + bf2f((uint16_t)(ef >> 16)));
  }
  float2 o; o.x = z0; o.y = z1;
  *(float2*)(ZF + (size_t)v * 512 + c) = o;
}

// ---------------- launch ----------------
extern "C" void kernel_launch(void* const* d_in, const int* in_sizes, int n_in,
                              void* d_out, int out_size, void* d_ws, size_t ws_size,
                              hipStream_t stream) {
  const float* visual = (const float*)d_in[0];
  const float* spatial = (const float*)d_in[1];
  const float* W_edge = (const float*)d_in[2];
  const float* b_edge = (const float*)d_in[3];
  const float* W_attn = (const float*)d_in[4];
  const float* b_attn = (const float*)d_in[5];
  const float* W_node = (const float*)d_in[6];
  const float* b_node = (const float*)d_in[7];
  const float* W_pred = (const float*)d_in[8];
  const float* b_pred = (const float*)d_in[9];
  const int* src = (const int*)d_in[10];
  const int* dst = (const int*)d_in[11];
  const int* toe = (const int*)d_in[12];
  float* out = (float*)d_out;

  char* ws = (char*)d_ws;
  float* A13 = (float*)(ws);                         // 4096x1024 f32 = 16 MB
  uint16_t* EF = (uint16_t*)(ws + 16777216);         // 61440x512 bf16 = 60 MB
  float* AATT = (float*)(ws + 79691776);             // 61440 f32
  float* ZF = (float*)(ws + 79937536);               // 4096x512 f32 = 8 MB
  uint16_t* NNF = (uint16_t*)(ws + 88326144);        // 4096x512 bf16 = 4 MB
  float* U13 = (float*)(ws + 92520448);              // 4096x1024 f32 = 16 MB
  // total 109,297,664 B

  hipMemsetAsync(AATT, 0, 61440 * sizeof(float), stream);

  const dim3 blk(256);
  const size_t D2 = (size_t)512 * 512;

  {  // A13 = visual @ [W1 | W3]   (M=4096, N=1024, K=512)
    GemmArgs a = {};
    a.Af = visual; a.B0 = W_edge; a.B1 = W_edge + 2 * D2; a.K = 512;
    a.Cf = A13; a.ldc = 1024;
    gemm_k<A_F32, E_PLAIN><<<dim3(32, 8), blk, 0, stream>>>(a);
  }
  {  // e_f = relu(A1[src] + spatial@W2 + A3[dst] + b_edge); attn partials
    GemmArgs a = {};
    a.Af = spatial; a.B0 = W_edge + D2; a.K = 512;
    a.bias = b_edge; a.wattn = W_attn;
    a.src = src; a.dst = dst; a.A13 = A13; a.EF = EF; a.AATT = AATT;
    gemm_k<A_F32, E_EDGE><<<dim3(480, 4), blk, 0, stream>>>(a);
  }
  node_reduce_k<<<4096, blk, 0, stream>>>(AATT, b_attn, visual, EF, ZF);
  {  // new_n_f = relu(visual@Wn1 + z_f@Wn2 + b_node)  (K=1024 virtual concat)
    GemmArgs a = {};
    a.Af = visual; a.Af2 = ZF; a.B0 = W_node; a.K = 1024;
    a.bias = b_node; a.NNF = NNF;
    gemm_k<A_DUALK, E_NODE><<<dim3(32, 4), blk, 0, stream>>>(a);
  }
  {  // U13 = new_n_f @ [Wp1 | Wp3]
    GemmArgs a = {};
    a.Ab = NNF; a.B0 = W_pred; a.B1 = W_pred + 2 * D2; a.K = 512;
    a.Cf = U13; a.ldc = 1024;
    gemm_k<A_BF16, E_PLAIN><<<dim3(32, 8), blk, 0, stream>>>(a);
  }
  {  // pred = relu(U1[ts] + spatial[toe]@Wp2 + U3[td] + b_pred)
    GemmArgs a = {};
    a.Af = spatial; a.gidx = toe; a.B0 = W_pred + D2; a.K = 512;
    a.bias = b_pred; a.toe = toe; a.src = src; a.dst = dst; a.U13 = U13; a.OUT = out;
    gemm_k<A_GATHER, E_PRED><<<dim3(30, 4), blk, 0, stream>>>(a);
  }
  (void)in_sizes; (void)n_in; (void)out_size; (void)ws_size;
}

// Round 2
// 242.211 us; speedup vs baseline: 1.5949x; 1.5949x over previous
//
#include <hip/hip_runtime.h>
#include <hip/hip_bf16.h>
#include <stdint.h>

// ---------------- common ----------------
#define BM 128
#define BN 128
// macro K-step = 64, staged as two [128][32] bf16 sub-tiles (m97-proven layout)

typedef __attribute__((ext_vector_type(8))) short bf16x8;
typedef __attribute__((ext_vector_type(4))) float f32x4;
typedef __attribute__((ext_vector_type(4))) uint32_t u32x4;

__device__ __forceinline__ short f2bf(float f) {
  union { float f; uint32_t u; } v; v.f = f;
  return (short)((v.u + 0x7FFFu + ((v.u >> 16) & 1u)) >> 16);  // RNE
}
__device__ __forceinline__ float bf2f(uint16_t s) {
  union { uint32_t u; float f; } v; v.u = ((uint32_t)s) << 16;
  return v.f;
}
__device__ __forceinline__ uint32_t pk2(float lo, float hi) {
  union { __hip_bfloat162 h; uint32_t u; } un;
  un.h = __float22bfloat162_rn(make_float2(lo, hi));  // v_cvt_pk_bf16_f32
  return un.u;
}
__device__ __forceinline__ void gload_lds16(const void* g, void* l) {
  __builtin_amdgcn_global_load_lds((const __attribute__((address_space(1))) void*)g,
                                   (__attribute__((address_space(3))) void*)l, 16, 0, 0);
}

enum { A_F32 = 0, A_DUALK = 1, A_BF16 = 2, A_GATHER = 3 };
enum { E_PLAIN = 0, E_EDGE = 1, E_NODE = 2, E_PRED = 3 };

struct GemmArgs {
  const float* Af;      // fp32 A (lda = 512)
  const float* Af2;     // second A source for A_DUALK (k >= 512)
  const uint16_t* Ab;   // bf16 A for A_BF16 (lda = 512)
  const int* gidx;      // row gather for A_GATHER
  const uint16_t* B0;   // B^T bf16 [N][K] row-major; out cols < 512
  const uint16_t* B1;   // out cols >= 512 (N=1024 case)
  int K;
  float* Cf; int ldc;   // E_PLAIN out
  const float* bias;
  const float* wattn;   // [512]
  const float* visf;    // visual (E_EDGE msg fold)
  const int* src; const int* dst; const int* toe;
  const float* A13;     // [4096,1024]
  const float* U13;     // [4096,1024]
  uint16_t* EF;         // MSG bf16 [61440,512]
  float* AATT;          // attn partials [61440]
  uint16_t* NNF;        // new_n_f bf16 [4096,512]
  float* OUT;           // pred [3840,512]
};

template <int AMODE, int EPI>
__global__ __launch_bounds__(256) void gemm_k(GemmArgs g) {
  __shared__ __align__(16) short As[2][BM * 32];
  __shared__ __align__(16) short Bs[2][BN * 32];
  const int tid = threadIdx.x;
  const int m0 = blockIdx.x * BM;
  const int n0g = blockIdx.y * BN;
  const int w = tid >> 6, lane = tid & 63;

  const uint16_t* Bp = g.B0;
  int n0 = n0g;
  if (n0g >= 512) { Bp = g.B1; n0 = n0g - 512; }

  // ---- gload_lds chunk geometry (B always; A in A_BF16 mode) ----
  const int gr = lane >> 2;          // row within 16-row group
  const int gk = (lane & 3) * 8;     // k element offset
  const uint16_t* gB[2]; int bofs[2];
#pragma unroll
  for (int c = 0; c < 2; ++c) {
    const int n = n0 + c * 64 + w * 16 + gr;
    gB[c] = Bp + (size_t)n * g.K + gk;
    bofs[c] = c * 2048 + w * 512;    // wave-uniform lds short-offset
  }
  const uint16_t* gA[2]; int aofs[2];
  if constexpr (AMODE == A_BF16) {
#pragma unroll
    for (int c = 0; c < 2; ++c) {
      gA[c] = g.Ab + (size_t)(m0 + c * 64 + w * 16 + gr) * 512 + gk;
      aofs[c] = c * 2048 + w * 512;
    }
  }
  // ---- reg-staged A geometry (fp32 modes) ----
  const int tr = tid >> 1, ch = tid & 1;
  const float* arow = nullptr; const float* arow2 = nullptr;
  int aofs_rs = 0;
  if constexpr (AMODE != A_BF16) {
    int ridx = m0 + tr;
    if constexpr (AMODE == A_GATHER) ridx = g.gidx[ridx];
    arow = g.Af + (size_t)ridx * 512 + ch * 16;
    if constexpr (AMODE == A_DUALK) arow2 = g.Af2 + (size_t)(m0 + tr) * 512 + ch * 16;
    aofs_rs = tr * 32 + ch * 16;
  }

  const int wm = w >> 1, wn = w & 1;
  const int lr = lane & 15, lg = lane >> 4;
  int aro[4], bro[4];
#pragma unroll
  for (int m = 0; m < 4; ++m) aro[m] = (wm * 64 + m * 16 + lr) * 32 + lg * 8;
#pragma unroll
  for (int n = 0; n < 4; ++n) bro[n] = (wn * 64 + n * 16 + lr) * 32 + lg * 8;

  f32x4 acc[4][4] = {};

  for (int k0 = 0; k0 < g.K; k0 += 64) {
    __syncthreads();
#pragma unroll
    for (int h = 0; h < 2; ++h) {
      const int kk = k0 + h * 32;
      if constexpr (AMODE == A_BF16) {
        gload_lds16(gA[0] + kk, &As[h][aofs[0]]);
        gload_lds16(gA[1] + kk, &As[h][aofs[1]]);
      } else {
        const float* ap = arow; int kkk = kk;
        if constexpr (AMODE == A_DUALK) {
          if (kk >= 512) { ap = arow2; kkk = kk - 512; }
        }
        const float4 f0 = *(const float4*)(ap + kkk);
        const float4 f1 = *(const float4*)(ap + kkk + 4);
        const float4 f2 = *(const float4*)(ap + kkk + 8);
        const float4 f3 = *(const float4*)(ap + kkk + 12);
        u32x4 lo, hi;
        lo[0] = pk2(f0.x, f0.y); lo[1] = pk2(f0.z, f0.w);
        lo[2] = pk2(f1.x, f1.y); lo[3] = pk2(f1.z, f1.w);
        hi[0] = pk2(f2.x, f2.y); hi[1] = pk2(f2.z, f2.w);
        hi[2] = pk2(f3.x, f3.y); hi[3] = pk2(f3.z, f3.w);
        *(u32x4*)&As[h][aofs_rs] = lo;
        *(u32x4*)&As[h][aofs_rs + 8] = hi;
      }
      gload_lds16(gB[0] + kk, &Bs[h][bofs[0]]);
      gload_lds16(gB[1] + kk, &Bs[h][bofs[1]]);
    }
    __syncthreads();
#pragma unroll
    for (int h = 0; h < 2; ++h) {
      bf16x8 av[4], bv[4];
#pragma unroll
      for (int m = 0; m < 4; ++m) av[m] = *(const bf16x8*)&As[h][aro[m]];
#pragma unroll
      for (int n = 0; n < 4; ++n) bv[n] = *(const bf16x8*)&Bs[h][bro[n]];
#pragma unroll
      for (int m = 0; m < 4; ++m)
#pragma unroll
        for (int n = 0; n < 4; ++n)
          acc[m][n] = __builtin_amdgcn_mfma_f32_16x16x32_bf16(av[m], bv[n], acc[m][n], 0, 0, 0);
    }
  }

  // ---- epilogue ----  C/D: col = lane&15, row = (lane>>4)*4 + reg
  const int rbase = m0 + wm * 64;
  const int cbase = n0g + wn * 64;

  if constexpr (EPI == E_PLAIN) {
#pragma unroll
    for (int m = 0; m < 4; ++m)
#pragma unroll
      for (int r = 0; r < 4; ++r) {
        const int row = rbase + m * 16 + lg * 4 + r;
#pragma unroll
        for (int n = 0; n < 4; ++n)
          g.Cf[(size_t)row * g.ldc + cbase + n * 16 + lr] = acc[m][n][r];
      }
  } else if constexpr (EPI == E_NODE) {
#pragma unroll
    for (int m = 0; m < 4; ++m)
#pragma unroll
      for (int r = 0; r < 4; ++r) {
        const int row = rbase + m * 16 + lg * 4 + r;
#pragma unroll
        for (int n = 0; n < 4; ++n) {
          const int col = cbase + n * 16 + lr;
          const float v = fmaxf(acc[m][n][r] + g.bias[col], 0.f);
          g.NNF[(size_t)row * 512 + col] = (uint16_t)f2bf(v);
        }
      }
  } else if constexpr (EPI == E_EDGE) {
    float bv[4], wv[4]; int cols[4];
#pragma unroll
    for (int n = 0; n < 4; ++n) {
      cols[n] = cbase + n * 16 + lr;
      bv[n] = g.bias[cols[n]];
      wv[n] = g.wattn[cols[n]];
    }
#pragma unroll
    for (int m = 0; m < 4; ++m)
#pragma unroll
      for (int r = 0; r < 4; ++r) {
        const int e = rbase + m * 16 + lg * 4 + r;
        const int se = g.src[e], de = g.dst[e];
        const float* a1 = g.A13 + (size_t)se * 1024;
        const float* a3 = g.A13 + (size_t)de * 1024 + 512;
        const float* vi = g.visf + (size_t)se * 512;
        float rp = 0.f;
#pragma unroll
        for (int n = 0; n < 4; ++n) {
          float v = acc[m][n][r] + a1[cols[n]] + a3[cols[n]] + bv[n];
          v = fmaxf(v, 0.f);
          rp += v * wv[n];
          g.EF[(size_t)e * 512 + cols[n]] = (uint16_t)f2bf(v + vi[cols[n]]);  // msg
        }
        for (int d = 1; d < 16; d <<= 1) rp += __shfl_xor(rp, d);
        if (lr == 0) atomicAdd(&g.AATT[e], rp);
      }
  } else {  // E_PRED
    float bv[4]; int cols[4];
#pragma unroll
    for (int n = 0; n < 4; ++n) { cols[n] = cbase + n * 16 + lr; bv[n] = g.bias[cols[n]]; }
#pragma unroll
    for (int m = 0; m < 4; ++m)
#pragma unroll
      for (int r = 0; r < 4; ++r) {
        const int row = rbase + m * 16 + lg * 4 + r;
        const int te = g.toe[row];
        const int ts = g.src[te], td = g.dst[te];
        const float* u1 = g.U13 + (size_t)ts * 1024;
        const float* u3 = g.U13 + (size_t)td * 1024 + 512;
#pragma unroll
        for (int n = 0; n < 4; ++n) {
          const float v = acc[m][n][r] + u1[cols[n]] + u3[cols[n]] + bv[n];
          g.OUT[(size_t)row * 512 + cols[n]] = fmaxf(v, 0.f);
        }
      }
  }
}

// ---------- weight transpose+convert: WT[n][k] = bf16(W[k][n]) ----------
__global__ __launch_bounds__(256) void trans_w_k(const float* We, const float* Wn,
                                                 const float* Wp, uint16_t* WT) {
  const int z = blockIdx.z;
  const float* src; uint16_t* dst; int ldo = 512, koff = 0;
  switch (z) {
    default:
    case 0: src = We;          dst = WT;           break;
    case 1: src = We + 262144; dst = WT + 262144;  break;
    case 2: src = We + 524288; dst = WT + 524288;  break;
    case 3: src = Wn;          dst = WT + 786432;  ldo = 1024; break;
    case 4: src = Wn + 262144; dst = WT + 786432;  ldo = 1024; koff = 512; break;
    case 5: src = Wp;          dst = WT + 1310720; break;
    case 6: src = Wp + 262144; dst = WT + 1572864; break;
    case 7: src = Wp + 524288; dst = WT + 1835008; break;
  }
  __shared__ float tile[32][33];
  const int tx = threadIdx.x, ty = threadIdx.y;  // 32 x 8
  const int kb = blockIdx.x * 32, nb = blockIdx.y * 32;
#pragma unroll
  for (int s = 0; s < 4; ++s)
    tile[ty + 8 * s][tx] = src[(size_t)(kb + ty + 8 * s) * 512 + nb + tx];
  __syncthreads();
#pragma unroll
  for (int s = 0; s < 4; ++s) {
    const int n = nb + ty + 8 * s, k = kb + tx;
    dst[(size_t)n * ldo + koff + k] = (uint16_t)f2bf(tile[tx][ty + 8 * s]);
  }
}

// ---------- per-node softmax over 15 incoming edges + weighted aggregate ----------
__global__ __launch_bounds__(256) void node_reduce_k(const float* AATT, const float* battn,
                                                     const uint16_t* MSG, float* ZF) {
  const int sub = threadIdx.x >> 7;  // 2 nodes per block
  const int t = threadIdx.x & 127;
  const int v = blockIdx.x * 2 + sub;
  const int gph = v >> 4, j = v & 15;
  __shared__ float sa_s[2][16];
  __shared__ float alf_s[2][16];
  __shared__ int eids_s[2][16];
  if (t < 15) {
    const int i = (t < j) ? t : t + 1;
    const int off = (j < i) ? j : (j - 1);
    const int eid = gph * 240 + i * 15 + off;  // DGL src-major edge id
    eids_s[sub][t] = eid;
    sa_s[sub][t] = fmaxf(AATT[eid] + battn[0], 0.f);
  }
  __syncthreads();
  float mx = -1e30f;
#pragma unroll
  for (int i = 0; i < 15; ++i) mx = fmaxf(mx, sa_s[sub][i]);
  float den = 0.f;
#pragma unroll
  for (int i = 0; i < 15; ++i) den += expf(sa_s[sub][i] - mx);
  if (t < 15) alf_s[sub][t] = expf(sa_s[sub][t] - mx) / den;
  __syncthreads();
  const int c = t * 4;
  float z0 = 0.f, z1 = 0.f, z2 = 0.f, z3 = 0.f;
#pragma unroll
  for (int i = 0; i < 15; ++i) {
    const float a = alf_s[sub][i];
    const ushort4 m4 = *(const ushort4*)(MSG + (size_t)eids_s[sub][i] * 512 + c);
    z0 += a * bf2f(m4.x); z1 += a * bf2f(m4.y);
    z2 += a * bf2f(m4.z); z3 += a * bf2f(m4.w);
  }
  float4 o; o.x = z0; o.y = z1; o.z = z2; o.w = z3;
  *(float4*)(ZF + (size_t)v * 512 + c) = o;
}

// ---------------- launch ----------------
extern "C" void kernel_launch(void* const* d_in, const int* in_sizes, int n_in,
                              void* d_out, int out_size, void* d_ws, size_t ws_size,
                              hipStream_t stream) {
  const float* visual = (const float*)d_in[0];
  const float* spatial = (const float*)d_in[1];
  const float* W_edge = (const float*)d_in[2];
  const float* b_edge = (const float*)d_in[3];
  const float* W_attn = (const float*)d_in[4];
  const float* b_attn = (const float*)d_in[5];
  const float* W_node = (const float*)d_in[6];
  const float* b_node = (const float*)d_in[7];
  const float* W_pred = (const float*)d_in[8];
  const float* b_pred = (const float*)d_in[9];
  const int* src = (const int*)d_in[10];
  const int* dst = (const int*)d_in[11];
  const int* toe = (const int*)d_in[12];
  float* out = (float*)d_out;

  char* ws = (char*)d_ws;
  uint16_t* WT = (uint16_t*)ws;                    // 4,194,304 B (bf16 W^T, 8 parts)
  float* A13 = (float*)(ws + 4194304);             // 16,777,216 B
  uint16_t* MSG = (uint16_t*)(ws + 20971520);      // 62,914,560 B
  float* AATT = (float*)(ws + 83886080);           // 245,760 B
  float* ZF = (float*)(ws + 84131840);             // 8,388,608 B  (end 92,520,448)
  float* U13 = A13;        // alias: A13 dead after edge GEMM
  uint16_t* NNF = MSG;     // alias: MSG dead after node_reduce

  trans_w_k<<<dim3(16, 16, 8), dim3(32, 8), 0, stream>>>(W_edge, W_node, W_pred, WT);
  hipMemsetAsync(AATT, 0, 61440 * sizeof(float), stream);

  const dim3 blk(256);
  {  // A13 = visual @ [W1 | W3]
    GemmArgs a = {};
    a.Af = visual; a.B0 = WT; a.B1 = WT + 524288; a.K = 512;
    a.Cf = A13; a.ldc = 1024;
    gemm_k<A_F32, E_PLAIN><<<dim3(32, 8), blk, 0, stream>>>(a);
  }
  {  // msg/e_f GEMM: spatial @ W2, fused epilogue
    GemmArgs a = {};
    a.Af = spatial; a.B0 = WT + 262144; a.K = 512;
    a.bias = b_edge; a.wattn = W_attn; a.visf = visual;
    a.src = src; a.dst = dst; a.A13 = A13; a.EF = MSG; a.AATT = AATT;
    gemm_k<A_F32, E_EDGE><<<dim3(480, 4), blk, 0, stream>>>(a);
  }
  node_reduce_k<<<2048, blk, 0, stream>>>(AATT, b_attn, MSG, ZF);
  {  // new_n_f = relu([visual | z_f] @ W_node + b)
    GemmArgs a = {};
    a.Af = visual; a.Af2 = ZF; a.B0 = WT + 786432; a.K = 1024;
    a.bias = b_node; a.NNF = NNF;
    gemm_k<A_DUALK, E_NODE><<<dim3(32, 4), blk, 0, stream>>>(a);
  }
  {  // U13 = new_n_f @ [Wp1 | Wp3]
    GemmArgs a = {};
    a.Ab = NNF; a.B0 = WT + 1310720; a.B1 = WT + 1835008; a.K = 512;
    a.Cf = U13; a.ldc = 1024;
    gemm_k<A_BF16, E_PLAIN><<<dim3(32, 8), blk, 0, stream>>>(a);
  }
  {  // pred = relu(U1[ts] + spatial[toe] @ Wp2 + U3[td] + b)
    GemmArgs a = {};
    a.Af = spatial; a.gidx = toe; a.B0 = WT + 1572864; a.K = 512;
    a.bias = b_pred; a.toe = toe; a.src = src; a.dst = dst; a.U13 = U13; a.OUT = out;
    gemm_k<A_GATHER, E_PRED><<<dim3(30, 4), blk, 0, stream>>>(a);
  }
  (void)in_sizes; (void)n_in; (void)out_size; (void)ws_size;
}